// Round 1
// baseline (327.657 us; speedup 1.0000x reference)
//
#include <hip/hip_runtime.h>

// LengthRegulator: predictor path in the reference is dead code
// (durations = target_durations overrides _pred). Outputs:
//   [0] padded [B, F, D] f32 = expand(x, target_durations)
//   [1] durations [B, T]     = target_durations as float
//
// R8: scatter -> GATHER restructure.
// The old expand was dual-mode (variable 0..7 load-gated row stores +
// predicated zerofill) and ran ~3x below the write roofline that the
// harness's own 1.07 GB fill proves reachable (~6.2 TB/s). Now:
//   Kernel A: per-batch scan AND a tok[b,f] source-index table (256 KiB ws).
//   Kernel B: one wave per output row; uniform 4 KB read -> 4 KB NT write.
// Ideal traffic ~32 MB read + 268 MB write ~= 50 us.

#define B_ 8
#define T_ 1024
#define D_ 1024
#define F_ 8192          // MAX_FRAMES = T * DMAX
#define DV4 (D_ / 4)     // 256 float4 per row
#define WPB 16           // waves (= output rows) per block (1024 threads)
#define NBLK ((B_ * F_) / WPB)   // 4096 blocks

typedef float vfloat4 __attribute__((ext_vector_type(4)));

// Kernel A: per-batch inclusive scan of durations (LDS Hillis-Steele),
// emits durations output (float), and the frame->token table:
//   tok[b,f] = t  for f in [cum[t-1], cum[t])
//   tok[b,f] = -1 for f in [cum[T-1], F)
__global__ void __launch_bounds__(1024) dur_scan_tok_kernel(
    const int* __restrict__ dur,     // [B, T]
    int* __restrict__ tok,           // [B, F] (workspace)
    float* __restrict__ out_dur)     // [B, T] (tail of d_out, float view)
{
    __shared__ int s[T_];
    const int b = blockIdx.x;
    const int t = threadIdx.x;

    const int d = dur[b * T_ + t];
    out_dur[b * T_ + t] = (float)d;

    s[t] = d;
    __syncthreads();
    #pragma unroll
    for (int off = 1; off < T_; off <<= 1) {
        int v = (t >= off) ? s[t - off] : 0;
        __syncthreads();
        s[t] += v;
        __syncthreads();
    }
    const int c1    = s[t];
    const int c0    = t ? s[t - 1] : 0;
    const int total = s[T_ - 1];              // <= 7*1024 = 7168 < F_

    int* tokb = tok + b * F_;
    for (int f = c0; f < c1; ++f)             // <= 7 writes per thread
        tokb[f] = t;
    for (int f = total + t; f < F_; f += T_)  // invalid tail
        tokb[f] = -1;
}

// Kernel B: gather. One 64-lane wave per output row (b,f):
// broadcast tok load, then 4x coalesced float4 load + 4x NT float4 store.
// Perfectly uniform work, dense streaming writes, x (32 MB) stays cached.
__global__ void __launch_bounds__(1024) expand_gather_kernel(
    const float* __restrict__ x,     // [B, T, D]
    const int* __restrict__ tok,     // [B, F]
    float* __restrict__ out)         // [B, F, D]
{
    const int wave = threadIdx.x >> 6;
    const int lane = threadIdx.x & 63;
    const int row  = blockIdx.x * WPB + wave;   // global row = b * F_ + f
    const int b    = row >> 13;                 // F_ = 8192

    const int tk = tok[row];                    // wave-uniform (broadcast)

    vfloat4* dst = reinterpret_cast<vfloat4*>(out)
                 + (size_t)row * DV4 + lane;

    if (tk >= 0) {
        const vfloat4* src = reinterpret_cast<const vfloat4*>(x)
                           + (size_t)(b * T_ + tk) * DV4 + lane;
        const vfloat4 v0 = src[0];
        const vfloat4 v1 = src[64];
        const vfloat4 v2 = src[128];
        const vfloat4 v3 = src[192];
        __builtin_nontemporal_store(v0, dst);
        __builtin_nontemporal_store(v1, dst + 64);
        __builtin_nontemporal_store(v2, dst + 128);
        __builtin_nontemporal_store(v3, dst + 192);
    } else {
        const vfloat4 z = {0.f, 0.f, 0.f, 0.f};
        __builtin_nontemporal_store(z, dst);
        __builtin_nontemporal_store(z, dst + 64);
        __builtin_nontemporal_store(z, dst + 128);
        __builtin_nontemporal_store(z, dst + 192);
    }
}

extern "C" void kernel_launch(void* const* d_in, const int* in_sizes, int n_in,
                              void* d_out, int out_size, void* d_ws, size_t ws_size,
                              hipStream_t stream)
{
    const float* x   = (const float*)d_in[0];
    const int*   dur = (const int*)d_in[1];
    // d_in[2..11] (conv/LN/linear weights) are dead code in the reference.

    float* out     = (float*)d_out;
    float* out_dur = out + (size_t)B_ * F_ * D_;   // durations chunk
    int*   tok     = (int*)d_ws;                   // B_*F_*4 = 256 KiB scratch

    dur_scan_tok_kernel<<<B_, T_, 0, stream>>>(dur, tok, out_dur);
    expand_gather_kernel<<<NBLK, 1024, 0, stream>>>(x, tok, out);
}